// Round 13
// baseline (151.290 us; speedup 1.0000x reference)
//
#include <hip/hip_runtime.h>
#include <hip/hip_bf16.h>
#include <cstdint>
#include <cstddef>

#define B_ROWS 16384
#define D_DIM  256
#define TEMP_INV 14.285714285714286f   // 1/0.07

#define NITER 16      // 64-col iterations per block (chunk = 1024 cols)

using frag_cd = __attribute__((ext_vector_type(4))) float;   // 4 fp32
using i32x4   = __attribute__((ext_vector_type(4))) int;     // one 16B chunk
using i32x8   = __attribute__((ext_vector_type(8))) int;     // 32B f8f6f4 operand

__device__ __forceinline__ void gld_lds16(const void* g, void* l) {
    __builtin_amdgcn_global_load_lds(
        (const __attribute__((address_space(1))) void*)g,
        (__attribute__((address_space(3))) void*)l,
        16, 0, 0);
}

// ---------------------------------------------------------------------------
// fp8 operand storage layout (R17, verified absmax=0): fragment-major.
// row group g = row>>4, r = row&15; k-byte kappa: kt = kappa>>7,
// chunk c = (kappa&127)>>4, h = c>>2, q = c&3, b = kappa&15.
// byte offset = g*4096 + kt*2048 + h*1024 + q*256 + r*16 + b.
// MFMA 16x16x128 fp8 fragment for lane (quad,l15): chunks c=quad (h0) and
// c=quad+4 (h1) of row l15's kt-slab == slab_base + lane*16 (+1024).
// => fragment load = one contiguous 1KB wave load; 64-col slab = 16KB linear.
// ---------------------------------------------------------------------------

// Kernel 1 (R18, verified): one block per 16-row group; 16 lanes/row norms,
// fragment-major fp8 pack via small LDS buffer, coalesced uint4 stores.
// Also zero-initializes row_sums/col_sums/out.
__global__ __launch_bounds__(256) void norm_diag_kernel(
    const float* __restrict__ q, const float* __restrict__ d,
    unsigned int* __restrict__ qn, unsigned int* __restrict__ dn,
    float* __restrict__ diag,
    float* __restrict__ row_sums, float* __restrict__ col_sums,
    float* __restrict__ out) {
    const int b = blockIdx.x;   // group index, 0..1023
    if (b < 64)            row_sums[b * 256 + threadIdx.x] = 0.0f;
    else if (b < 128)      col_sums[(b - 64) * 256 + threadIdx.x] = 0.0f;
    else if (b == 128 && threadIdx.x == 0) out[0] = 0.0f;

    const int t    = threadIdx.x;
    const int lane = t & 63;
    const int w    = t >> 6;
    const int l15  = lane & 15;
    const int rw   = lane >> 4;          // row within wave's 4
    const int r    = w * 4 + rw;         // row & 15 (0..15)
    const int row  = b * 16 + r;

    const float4* qr = (const float4*)(q + (size_t)row * D_DIM);
    const float4* dr = (const float4*)(d + (size_t)row * D_DIM);
    float4 qv[4], dv[4];
    float qss = 0.f, dss = 0.f, qd = 0.f;
#pragma unroll
    for (int p = 0; p < 4; ++p) {
        qv[p] = qr[l15 + 16 * p];
        dv[p] = dr[l15 + 16 * p];
        qss += qv[p].x*qv[p].x + qv[p].y*qv[p].y + qv[p].z*qv[p].z + qv[p].w*qv[p].w;
        dss += dv[p].x*dv[p].x + dv[p].y*dv[p].y + dv[p].z*dv[p].z + dv[p].w*dv[p].w;
        qd  += qv[p].x*dv[p].x + qv[p].y*dv[p].y + qv[p].z*dv[p].z + qv[p].w*dv[p].w;
    }
#pragma unroll
    for (int off = 1; off < 16; off <<= 1) {
        qss += __shfl_xor(qss, off);
        dss += __shfl_xor(dss, off);
        qd  += __shfl_xor(qd,  off);
    }
    const float qinv = 1.0f / fmaxf(sqrtf(qss), 1e-12f);
    const float dinv = 1.0f / fmaxf(sqrtf(dss), 1e-12f);

    __shared__ unsigned int qbuf[1024], dbuf[1024];
#pragma unroll
    for (int p = 0; p < 4; ++p) {
        const int jw = l15 + 16 * p;     // word index in row, 0..63 (kappa=4*jw)
        int qp = 0, dp = 0;
        qp = __builtin_amdgcn_cvt_pk_fp8_f32(qv[p].x * qinv, qv[p].y * qinv, qp, false);
        qp = __builtin_amdgcn_cvt_pk_fp8_f32(qv[p].z * qinv, qv[p].w * qinv, qp, true);
        dp = __builtin_amdgcn_cvt_pk_fp8_f32(dv[p].x * dinv, dv[p].y * dinv, dp, false);
        dp = __builtin_amdgcn_cvt_pk_fp8_f32(dv[p].z * dinv, dv[p].w * dinv, dp, true);
        const int c    = (jw & 31) >> 2;
        const int widx = ((jw >> 5) << 9) | ((c >> 2) << 8) | ((c & 3) << 6)
                       | (r << 2) | (jw & 3);
        qbuf[widx] = (unsigned int)qp;
        dbuf[widx] = (unsigned int)dp;
    }
    if (l15 == 0) diag[row] = qd * qinv * dinv * TEMP_INV;
    __syncthreads();
    ((uint4*)qn)[(size_t)b * 256 + t] = ((const uint4*)qbuf)[t];
    ((uint4*)dn)[(size_t)b * 256 + t] = ((const uint4*)dbuf)[t];
}

// Kernel 2 (R28): cross-iteration epilogue pipelining (dual accumulator sets).
// Verified model (R20/R23/R27): MfmaUtil = waves/SIMD x per-wave MFMA duty
// (17%); duty is low because ds_read -> MFMA -> epilogue is serially chained
// within the wave. Occupancy multiplies a small number (R23/R24/R27 nulls).
// This round raises DUTY: two acc sets; per iter
//   HALF(accA) -> EPI(accB = prev half) -> HALF(accB) -> EPI(accA = this half)
// Each EPI (~325 issue-cyc of pk_fma/exp2/pk_add) issues in the shadow of a
// 16-MFMA cluster (~480 pipe-cyc) on which it has NO dependence (its acc
// completed a full barrier+stage+read earlier -- unlike R21's intra-iter
// variant whose producer MFMAs were ~30cyc prior). Regs: A 64 + 2x acc 32 +
// b8 16 + rvu 16 + misc ~ 176 <= 256 cap at (256,2) -- big margin, no remat
// (R26 lesson). Grid 1024, 2 blocks/CU uniform (R20 residency); sync order
// R23-proven; counted vmcnt(4) stays correct with extra atomics in flight
// (certifies all but the newest 4 VM ops, which always includes this iter's
// stage). Discriminators: FETCH ~18.5MB, gemm < 80us, MfmaUtil > 38%.
__global__ __launch_bounds__(256, 2) void gemm_lse_kernel(
    const unsigned char* __restrict__ qn, const unsigned char* __restrict__ dn,
    float* __restrict__ row_sums, float* __restrict__ col_sums) {
    __shared__ unsigned char ldsB[3][16384];   // 48 KB: 3 x (64 cols x 256 K)

    const int t    = threadIdx.x;
    const int lane = t & 63;
    const int w    = t >> 6;          // 0..3 : which 64-row strip
    const int l15  = lane & 15;
    const int quad = lane >> 4;

    // Grid: 1024 blocks = 64 row-groups x 16 col-chunks; 2 chunks per XCD.
    const int id   = blockIdx.x;
    const int xcd  = id & 7;
    const int i    = id >> 3;               // 0..127
    const int chunk   = (xcd << 1) | (i & 1);   // 0..15
    const int rowg    = i >> 1;                 // 0..63
    const int rowBase = rowg * 256;
    const int colChunkBase = chunk * 1024;

    union OpU { i32x8 v; i32x4 h[2]; };

    // ---- Persistent A: 8 frags (4 mi x 2 kt) = 64 VGPRs, 16 coalesced loads.
    const unsigned char* aB = qn + ((size_t)((rowBase >> 4) + w * 4) << 12) + lane * 16;
    OpU a8[4][2];
#pragma unroll
    for (int mi = 0; mi < 4; ++mi)
#pragma unroll
        for (int kt = 0; kt < 2; ++kt) {
            a8[mi][kt].h[0] = *(const i32x4*)(aB + mi * 4096 + kt * 2048);
            a8[mi][kt].h[1] = *(const i32x4*)(aB + mi * 4096 + kt * 2048 + 1024);
        }

    // ---- B stream: iter it occupies 16KB linear slab at bG + it*16384.
    const unsigned char* bG = dn + ((size_t)(colChunkBase >> 4) << 12);

#define STAGE(bufidx, j)                                                      \
    {                                                                          \
        const unsigned char* gsrc = bG + (size_t)(j) * 16384;                  \
        unsigned char* ldst = &ldsB[bufidx][0];                                \
        _Pragma("unroll")                                                      \
        for (int ii = 0; ii < 4; ++ii)                                         \
            gld_lds16(gsrc + ii * 4096 + t * 16, ldst + ii * 4096 + t * 16);   \
    }

    // Prologue: stage iters 0 and 1 (8 loads in flight per thread).
    STAGE(0, 0)
    STAGE(1, 1)

    union RV { frag_cd v[4]; float f[16]; } rvu;   // per-row exp-sum accumulators
#pragma unroll
    for (int k = 0; k < 4; ++k) rvu.v[k] = (frag_cd){0.f, 0.f, 0.f, 0.f};

    const float C2 = TEMP_INV * 1.44269504088896f;
    const frag_cd zf = (frag_cd){0.f, 0.f, 0.f, 0.f};

    // One 32-col half: 2 B frags/kt, 16 MFMA into ACC (kt0 with C=zero).
#define HALF(ACC, bH)                                                         \
    {                                                                          \
        OpU b8[2];                                                             \
        _Pragma("unroll")                                                      \
        for (int ni = 0; ni < 2; ++ni) {                                       \
            b8[ni].h[0] = *(const i32x4*)((bH) + ni * 4096);                   \
            b8[ni].h[1] = *(const i32x4*)((bH) + ni * 4096 + 1024);            \
        }                                                                      \
        __builtin_amdgcn_s_setprio(1);                                         \
        _Pragma("unroll")                                                      \
        for (int mi = 0; mi < 4; ++mi)                                         \
            _Pragma("unroll")                                                  \
            for (int ni = 0; ni < 2; ++ni)                                     \
                ACC[mi][ni] = __builtin_amdgcn_mfma_scale_f32_16x16x128_f8f6f4(\
                    a8[mi][0].v, b8[ni].v, zf,                                 \
                    0, 0, 0, 0x7F7F7F7F, 0, 0x7F7F7F7F);                       \
        __builtin_amdgcn_s_setprio(0);                                         \
        _Pragma("unroll")                                                      \
        for (int ni = 0; ni < 2; ++ni) {                                       \
            b8[ni].h[0] = *(const i32x4*)((bH) + ni * 4096 + 2048);            \
            b8[ni].h[1] = *(const i32x4*)((bH) + ni * 4096 + 3072);            \
        }                                                                      \
        __builtin_amdgcn_s_setprio(1);                                         \
        _Pragma("unroll")                                                      \
        for (int mi = 0; mi < 4; ++mi)                                         \
            _Pragma("unroll")                                                  \
            for (int ni = 0; ni < 2; ++ni)                                     \
                ACC[mi][ni] = __builtin_amdgcn_mfma_scale_f32_16x16x128_f8f6f4(\
                    a8[mi][1].v, b8[ni].v, ACC[mi][ni],                        \
                    0, 0, 0, 0x7F7F7F7F, 0, 0x7F7F7F7F);                       \
        __builtin_amdgcn_s_setprio(0);                                         \
    }

    // Epilogue of one (completed) 32-col half. cols: (colbase)+0..31.
    // Full quad-reduce of the 2 col partials, one predicated atomic.
#define EPI(ACC, colbase)                                                     \
    {                                                                          \
        float cv0 = 0.f, cv1 = 0.f;                                            \
        _Pragma("unroll")                                                      \
        for (int mi = 0; mi < 4; ++mi) {                                       \
            frag_cd tt = ACC[mi][0] * C2 - C2;                                 \
            frag_cd e;                                                         \
            _Pragma("unroll")                                                  \
            for (int rr = 0; rr < 4; ++rr)                                     \
                e[rr] = __builtin_amdgcn_exp2f(tt[rr]);                        \
            rvu.v[mi] += e;                                                    \
            cv0 += (e[0] + e[1]) + (e[2] + e[3]);                              \
            tt = ACC[mi][1] * C2 - C2;                                         \
            _Pragma("unroll")                                                  \
            for (int rr = 0; rr < 4; ++rr)                                     \
                e[rr] = __builtin_amdgcn_exp2f(tt[rr]);                        \
            rvu.v[mi] += e;                                                    \
            cv1 += (e[0] + e[1]) + (e[2] + e[3]);                              \
        }                                                                      \
        cv0 += __shfl_xor(cv0, 16); cv0 += __shfl_xor(cv0, 32);                \
        cv1 += __shfl_xor(cv1, 16); cv1 += __shfl_xor(cv1, 32);                \
        if (quad < 2)                                                          \
            atomicAdd(&col_sums[(colbase) + quad * 16 + l15],                  \
                      quad ? cv1 : cv0);                                       \
    }

    frag_cd accA[4][2], accB[4][2];   // dual acc sets (static names, rule #20)

    int cur = 0;   // buffer holding iter it
#pragma unroll 1
    for (int it = 0; it < NITER; ++it) {
        // (1) certify own loads (all but newest 4 VM ops -> includes S_it);
        // (2) barrier: all waves certified + done reading the reuse target.
        if (it == NITER - 1) asm volatile("s_waitcnt vmcnt(0)" ::: "memory");
        else                 asm volatile("s_waitcnt vmcnt(4)" ::: "memory");
        __builtin_amdgcn_s_barrier();
        asm volatile("" ::: "memory");

        // Stage iter it+2 into the buffer freed at iter it-1.
        const int nxt = (cur + 2 >= 3) ? cur - 1 : cur + 2;
        if (it + 2 < NITER) STAGE(nxt, it + 2)

        const unsigned char* bL = &ldsB[cur][0] + lane * 16;

        // half0 -> accA; then epilogue of PREVIOUS iter's half1 (accB),
        // issuing in the shadow of accA's MFMA pipe drain.
        HALF(accA, bL)
        if (it) EPI(accB, colChunkBase + (it - 1) * 64 + 32)

        // half1 -> accB; then epilogue of THIS iter's half0 (accA),
        // issuing in the shadow of accB's MFMA pipe drain.
        HALF(accB, bL + 8192)
        EPI(accA, colChunkBase + it * 64)

        cur = (cur + 1 >= 3) ? 0 : cur + 1;
    }
    // tail: epilogue of the final half1
    EPI(accB, colChunkBase + (NITER - 1) * 64 + 32)

#undef STAGE
#undef HALF
#undef EPI

    // ---- final row butterfly all-reduce over the 16 lanes of each quad ----
    // 16 row partials (p = mi*4+rr); end: f[0] <-> p = l15.
#pragma unroll
    for (int s = 0; s < 4; ++s) {
        const bool bb = (l15 >> s) & 1;
#pragma unroll
        for (int k = 0; k < (8 >> s); ++k) {
            const float a0 = rvu.f[2 * k], a1 = rvu.f[2 * k + 1];
            const float keep = bb ? a1 : a0;
            const float send = bb ? a0 : a1;
            rvu.f[k] = keep + __shfl_xor(send, 1 << s);
        }
    }
    atomicAdd(&row_sums[rowBase + w * 64 + (l15 >> 2) * 16 + quad * 4 + (l15 & 3)],
              rvu.f[0]);
}

// Kernel 3 (parallel): each block reduces 256 rows, atomicAdd into zeroed out[0].
__global__ __launch_bounds__(256) void finalize_kernel(
    const float* __restrict__ rs, const float* __restrict__ cs,
    const float* __restrict__ dg, float* __restrict__ out) {
    const int i = blockIdx.x * 256 + threadIdx.x;
    float s = logf(rs[i]) + logf(cs[i]) - 2.0f * dg[i];
#pragma unroll
    for (int off = 32; off; off >>= 1) s += __shfl_down(s, off);
    __shared__ float buf[4];
    if ((threadIdx.x & 63) == 0) buf[threadIdx.x >> 6] = s;
    __syncthreads();
    if (threadIdx.x == 0) {
        float tot = (buf[0] + buf[1] + buf[2] + buf[3]) / (2.0f * B_ROWS);
        if (blockIdx.x == 0) tot += TEMP_INV;   // undo the fixed exp shift
        atomicAdd(out, tot);
    }
}

extern "C" void kernel_launch(void* const* d_in, const int* in_sizes, int n_in,
                              void* d_out, int out_size, void* d_ws, size_t ws_size,
                              hipStream_t stream) {
    const float* q = (const float*)d_in[0];
    const float* d = (const float*)d_in[1];
    float* out = (float*)d_out;

    char* ws = (char*)d_ws;
    unsigned char* qn = (unsigned char*)ws;                         // 4 MB fp8 (fragment-major)
    unsigned char* dn = qn + (size_t)B_ROWS * D_DIM;                // 4 MB fp8 (fragment-major)
    float* row_sums = (float*)(ws + 2 * (size_t)B_ROWS * D_DIM);
    float* col_sums = row_sums + B_ROWS;
    float* diag     = col_sums + B_ROWS;

    norm_diag_kernel<<<B_ROWS / 16, 256, 0, stream>>>(
        q, d, (unsigned int*)qn, (unsigned int*)dn, diag, row_sums, col_sums, out);
    gemm_lse_kernel<<<(B_ROWS / 256) * (B_ROWS / 1024), 256, 0, stream>>>(
        qn, dn, row_sums, col_sums);
    finalize_kernel<<<B_ROWS / 256, 256, 0, stream>>>(row_sums, col_sums, diag, out);
}